// Round 16
// baseline (203.286 us; speedup 1.0000x reference)
//
#include <hip/hip_runtime.h>
#include <math.h>

#define BATCH   16384
#define HD      24      // LSTM hidden size
#define NOUTC   24
#define NHID    16
#define NSTEPS  47
#define NG      96
#define NTG     8       // lanes (j-slot groups) per element
#define JPW     3       // j-slots per group
#define GPW     12      // gates per group
#define EPW     8       // elements per wave (64/NTG)
#define GRP     32      // elements per block
#define THREADS 256     // 4 waves; grid 512; zero per-step barriers

typedef float v2f __attribute__((ext_vector_type(2)));
union F4 { float4 f; v2f h[2]; };
union Acc12 { v2f v[6]; float f[12]; };

__device__ __forceinline__ v2f pk_fma(v2f a, v2f b, v2f c) {
    v2f d;
    asm("v_pk_fma_f32 %0, %1, %2, %3" : "=v"(d) : "v"(a), "v"(b), "v"(c));
    return d;  // per-component IEEE fma: bit-identical to 2x fmaf
}

__device__ __forceinline__ float fast_sigmoid(float x) {
    float t = __expf(-x);
    return __builtin_amdgcn_rcpf(1.0f + t);
}
__device__ __forceinline__ float fast_tanh(float x) {
    float ax = fabsf(x);
    float t  = __expf(-2.0f * ax);
    float r  = (1.0f - t) * __builtin_amdgcn_rcpf(1.0f + t);
    return copysignf(r, x);
}

__global__ __launch_bounds__(THREADS, 4) void policy_kernel(
    const float* __restrict__ W_ih, const float* __restrict__ W_hh,
    const float* __restrict__ b_ih, const float* __restrict__ b_hh,
    const float* __restrict__ Wl,   const float* __restrict__ bl,
    const float* __restrict__ rnd,  float* __restrict__ out)
{
    __shared__ float sWihB[NG][25];                     // [g][c] + bias folded (gather)
    __shared__ float sBias[NG];                         // b_ih + b_hh (step 0)
    __shared__ __align__(16) float sWhhP[HD][NTG][GPW]; // [k][g][t*3+i] : gate = t*24+3g+i
    __shared__ __align__(16) float sWlP[HD][NTG][4];    // [k][g][i] : logit col n = 3g+i (pad 4)
    __shared__ float sBl[NOUTC];
    __shared__ float sPr[GRP][NSTEPS + 1];
    __shared__ unsigned char sAct8[GRP][NSTEPS + 1];

    const int tid  = threadIdx.x;
    const int lane = tid & 63;
    const int wv   = tid >> 6;
    const int g    = lane >> 3;          // j-slot group 0..7
    const int e8   = lane & 7;           // element within wave
    const int elem = wv * EPW + e8;      // element within block
    const int b    = blockIdx.x * GRP + elem;

    // ---- staging (once per block) ----
    for (int i = tid; i < NG * HD; i += THREADS) {
        int gg = i / HD, k = i % HD;
        float bs = b_ih[gg] + b_hh[gg];
        sWihB[gg][k] = W_ih[i] + bs;
        int t = gg / 24, rem = gg % 24;
        sWhhP[k][rem / 3][t * 3 + rem % 3] = W_hh[i];
    }
    for (int i = tid; i < NOUTC * HD; i += THREADS) {
        int n = i / HD, k = i % HD;
        sWlP[k][n / 3][n % 3] = Wl[i];
    }
    if (tid < NG)    sBias[tid] = b_ih[tid] + b_hh[tid];
    if (tid < NOUTC) sBl[tid]   = bl[tid];
    __syncthreads();                    // weights visible; ONLY barrier until writeout

    float cst[JPW]  = {0.f, 0.f, 0.f};
    float hloc[JPW] = {0.f, 0.f, 0.f};
    Acc12 acc;                          // GEMV h-term partials; h0=0 -> exactly 0
    #pragma unroll
    for (int q = 0; q < 6; ++q) acc.v[q] = (v2f){0.f, 0.f};
    int actE = 0;

    for (int s = 0; s < NSTEPS; ++s) {
        const float r = rnd[s * BATCH + b];

        // ---- complete gates: a_ = GEMV-partial + gather row (bias folded) ----
        float a_[GPW];
        if (s == 0) {
            #pragma unroll
            for (int t = 0; t < 4; ++t)
                #pragma unroll
                for (int i = 0; i < JPW; ++i)
                    a_[t * JPW + i] = acc.f[t * JPW + i] + sBias[t * 24 + 3 * g + i];
        } else {
            #pragma unroll
            for (int t = 0; t < 4; ++t)
                #pragma unroll
                for (int i = 0; i < JPW; ++i)
                    a_[t * JPW + i] = acc.f[t * JPW + i] + sWihB[t * 24 + 3 * g + i][actE];
        }

        // ---- LSTM cell for own 3 j's (h stays in registers) ----
        #pragma unroll
        for (int i = 0; i < JPW; ++i) {
            float ig = a_[i], fg = a_[JPW + i], gg_ = a_[2 * JPW + i], og = a_[3 * JPW + i];
            float si = fast_sigmoid(ig);
            float sf = fast_sigmoid(fg);
            float so = fast_sigmoid(og);
            float tg = fast_tanh(gg_);
            float cj = sf * cst[i] + si * tg;
            cst[i] = cj;
            hloc[i] = so * fast_tanh(cj);
        }

        // ---- merged k-loop: logits(s) + gates-GEMV(s+1); h via shfl (no barrier) ----
        v2f  l01 = (v2f){0.f, 0.f};
        float l2 = 0.f;
        #pragma unroll
        for (int q = 0; q < 6; ++q) acc.v[q] = (v2f){0.f, 0.f};
        #pragma unroll 4
        for (int k = 0; k < HD; ++k) {
            float hown = (k % 3 == 0) ? hloc[0] : (k % 3 == 1) ? hloc[1] : hloc[2];
            float hk = __shfl(hown, (k / 3) * NTG + e8, 64);     // owner lane, exact bits
            v2f hk2; hk2.x = hk; hk2.y = hk;
            const float* wp = &sWhhP[k][g][0];
            F4 u0, u1, u2;
            u0.f = *(const float4*)&wp[0];
            u1.f = *(const float4*)&wp[4];
            u2.f = *(const float4*)&wp[8];
            acc.v[0] = pk_fma(hk2, u0.h[0], acc.v[0]);
            acc.v[1] = pk_fma(hk2, u0.h[1], acc.v[1]);
            acc.v[2] = pk_fma(hk2, u1.h[0], acc.v[2]);
            acc.v[3] = pk_fma(hk2, u1.h[1], acc.v[3]);
            acc.v[4] = pk_fma(hk2, u2.h[0], acc.v[4]);
            acc.v[5] = pk_fma(hk2, u2.h[1], acc.v[5]);
            v2f lv = *(const v2f*)&sWlP[k][g][0];
            l01 = pk_fma(hk2, lv, l01);
            l2  = fmaf(hk, sWlP[k][g][2], l2);
        }
        float l0 = l01.x + sBl[3 * g + 0];
        float l1 = l01.y + sBl[3 * g + 1];
        l2 += sBl[3 * g + 2];

        // ---- finish: gather logits via shfl, then exact sequential code ----
        const int  cnt = (s + 1) >> 1;
        const bool odd = (s & 1) != 0;
        float Z = 0.f, cum = 0.f, ea = 0.f, m = -INFINITY, pr;
        int a = 0;
        bool found = false;
        if (odd) {
            float v[NOUTC];
            #pragma unroll
            for (int n = 0; n < NOUTC; ++n) {
                float sv = (n % 3 == 0) ? l0 : (n % 3 == 1) ? l1 : l2;   // static select
                v[n] = __shfl(sv, (n / 3) * NTG + e8, 64);
            }
            #pragma unroll
            for (int n = 0; n < NOUTC; ++n) m = fmaxf(m, (n < cnt) ? v[n] : -INFINITY);
            #pragma unroll
            for (int n = 0; n < NOUTC; ++n) v[n] = (n < cnt) ? __expf(v[n] - m) : 0.f;
            #pragma unroll
            for (int n = 0; n < NOUTC; ++n) Z += v[n];                   // sequential 0..23
            const float rZ = r * Z;
            #pragma unroll
            for (int n = 0; n < NOUTC; ++n) {
                cum += v[n];
                if (!found && cum > rZ) { found = true; a = n; ea = v[n]; }
            }
            if (!found) { a = 0; ea = v[0]; }
            pr = ea / Z;                                                 // IEEE div
        } else {
            float v8[8];
            #pragma unroll
            for (int i = 0; i < 8; ++i) {
                int n = NHID + i;
                float sv = (n % 3 == 0) ? l0 : (n % 3 == 1) ? l1 : l2;
                v8[i] = __shfl(sv, (n / 3) * NTG + e8, 64);
            }
            #pragma unroll
            for (int i = 0; i < 8; ++i) m = fmaxf(m, v8[i]);
            #pragma unroll
            for (int i = 0; i < 8; ++i) v8[i] = __expf(v8[i] - m);
            #pragma unroll
            for (int i = 0; i < 8; ++i) Z += v8[i];                      // sequential 16..23
            const float rZ = r * Z;
            #pragma unroll
            for (int i = 0; i < 8; ++i) {
                cum += v8[i];
                if (!found && cum > rZ) { found = true; a = NHID + i; ea = v8[i]; }
            }
            if (!found) { a = 0; ea = 0.f; }                             // ref: p[0]=0 even steps
            pr = ea / Z;
        }

        if (g == 0) { sPr[elem][s] = pr; sAct8[elem][s] = (unsigned char)a; }
        actE = a;                                       // identical in all 8 lanes of the element
    }

    __syncthreads();
    // ---- coalesced write-out ----
    const int base = blockIdx.x * GRP * NSTEPS;
    for (int i = tid; i < GRP * NSTEPS; i += THREADS) {
        int rr = i / NSTEPS, ss = i - rr * NSTEPS;
        out[base + i]                          = sPr[rr][ss];
        out[(size_t)BATCH * NSTEPS + base + i] = (float)sAct8[rr][ss];
    }
}

extern "C" void kernel_launch(void* const* d_in, const int* in_sizes, int n_in,
                              void* d_out, int out_size, void* d_ws, size_t ws_size,
                              hipStream_t stream) {
    const float* W_ih = (const float*)d_in[0];
    const float* W_hh = (const float*)d_in[1];
    const float* b_ih = (const float*)d_in[2];
    const float* b_hh = (const float*)d_in[3];
    const float* Wl   = (const float*)d_in[4];
    const float* bl   = (const float*)d_in[5];
    const float* rnd  = (const float*)d_in[6];
    float* o = (float*)d_out;

    policy_kernel<<<BATCH / GRP, THREADS, 0, stream>>>(W_ih, W_hh, b_ih, b_hh, Wl, bl, rnd, o);
}